// Round 1
// baseline (3489.723 us; speedup 1.0000x reference)
//
#include <hip/hip_runtime.h>
#include <hip/hip_bf16.h>
#include <math.h>

// ---------------------------------------------------------------------------
// CorrNet forward, MI355X. Round 1: correct fp32 baseline.
// Pipeline:
//   k_init     : zero global-max + packed-argmax scratch
//   k_mlp14    : layers 1-4 (Lin+LeakyReLU+GN), writes f[n,128], atomicMax col-max g[128]
//   k_mlp57    : layers 5-7 (+concat g, + row L2-normalize) -> ov/op into d_out
//   k_argmax   : fused ov@op.T + per-row (max,argmax), packed u64 atomicMax merge
//   k_oc       : gather X=op[idx], layer8 + W9 -> oc
// All GroupNorm groups are exactly 32 channels -> half-wave shuffle reductions.
// ---------------------------------------------------------------------------

#define WPB 4  // waves per block for the MLP kernels

__device__ __forceinline__ float rsum32(float v) {
  v += __shfl_xor(v, 1);
  v += __shfl_xor(v, 2);
  v += __shfl_xor(v, 4);
  v += __shfl_xor(v, 8);
  v += __shfl_xor(v, 16);
  return v;
}
__device__ __forceinline__ float rsum64(float v) {
  v = rsum32(v);
  v += __shfl_xor(v, 32);
  return v;
}

// order-preserving float<->uint encoding (monotonic for all finite values)
__device__ __forceinline__ unsigned fenc(float f) {
  unsigned u = __float_as_uint(f);
  return (u & 0x80000000u) ? ~u : (u | 0x80000000u);
}
__device__ __forceinline__ float fdec(unsigned k) {
  return __uint_as_float((k & 0x80000000u) ? (k ^ 0x80000000u) : ~k);
}

// Linear (x @ W.T + b) -> LeakyReLU(0.2) -> GroupNorm(32-channel groups).
// Wave-cooperative: lane owns channel c = lane (+64). `in` is LDS (broadcast reads).
// All instantiations have every lane active for each j.
template<int OUT_C, int IN_C>
__device__ __forceinline__ void lin_gn(int lane,
    const float* __restrict__ W, const float* __restrict__ b,
    const float* __restrict__ gm, const float* __restrict__ be,
    const float* __restrict__ in, float out[2])
{
  constexpr int J = (OUT_C + 63) / 64;
  const float4* in4 = reinterpret_cast<const float4*>(in);
  float acc[J];
  const float4* w4[J];
#pragma unroll
  for (int j = 0; j < J; ++j) {
    acc[j] = b[lane + 64 * j];
    w4[j] = reinterpret_cast<const float4*>(W + (size_t)(lane + 64 * j) * IN_C);
  }
#pragma unroll
  for (int k = 0; k < IN_C / 4; ++k) {
    float4 v = in4[k];
#pragma unroll
    for (int j = 0; j < J; ++j) {
      float4 w = w4[j][k];
      acc[j] += w.x * v.x + w.y * v.y + w.z * v.z + w.w * v.w;
    }
  }
#pragma unroll
  for (int j = 0; j < J; ++j) {
    const int c = lane + 64 * j;
    float a = acc[j];
    a = a >= 0.f ? a : 0.2f * a;            // LeakyReLU(0.2)
    float s1 = rsum32(a);                    // group = 32 consecutive channels
    float s2 = rsum32(a * a);                //        = half-wave
    float mu = s1 * (1.f / 32.f);
    float var = s2 * (1.f / 32.f) - mu * mu;
    float r = rsqrtf(var + 1e-5f);
    out[j] = (a - mu) * r * gm[c] + be[c];
  }
}

// -------------------------------- init -------------------------------------
__global__ void k_init(unsigned* __restrict__ gv, unsigned* __restrict__ gp,
                       unsigned long long* __restrict__ best, int n)
{
  int i = blockIdx.x * blockDim.x + threadIdx.x;
  if (i < 128) { gv[i] = 0u; gp[i] = 0u; }     // fenc floor
  for (int k = i; k < n; k += gridDim.x * blockDim.x) best[k] = 0ull;
}

// ------------------------- layers 1-4 + col-max ----------------------------
__global__ __launch_bounds__(256) void k_mlp14(
    const float* __restrict__ x, int n,
    const float* __restrict__ W1, const float* __restrict__ b1, const float* __restrict__ g1, const float* __restrict__ be1,
    const float* __restrict__ W2, const float* __restrict__ b2, const float* __restrict__ g2, const float* __restrict__ be2,
    const float* __restrict__ W3, const float* __restrict__ b3, const float* __restrict__ g3, const float* __restrict__ be3,
    const float* __restrict__ W4, const float* __restrict__ b4, const float* __restrict__ g4, const float* __restrict__ be4,
    float* __restrict__ fOut, unsigned* __restrict__ gMax)
{
  __shared__ float buf[WPB][2][128];
  __shared__ float cms[WPB][128];
  const int wave = threadIdx.x >> 6, lane = threadIdx.x & 63;
  float* A = buf[wave][0];
  float* B = buf[wave][1];
  float cm0 = -3.4e38f, cm1 = -3.4e38f;
  const int gw = blockIdx.x * WPB + wave;
  const int nw = gridDim.x * WPB;
  for (int p = gw; p < n; p += nw) {       // n % nw == 0 -> uniform trip count
    const float x0 = x[3 * p], x1 = x[3 * p + 1], x2 = x[3 * p + 2];
    {   // layer1: 3->32, groups=1 (32-ch group)
      float a = 0.f;
      if (lane < 32)
        a = b1[lane] + W1[lane * 3] * x0 + W1[lane * 3 + 1] * x1 + W1[lane * 3 + 2] * x2;
      a = a >= 0.f ? a : 0.2f * a;
      float s1 = rsum32(a), s2 = rsum32(a * a);
      float mu = s1 * (1.f / 32.f);
      float var = s2 * (1.f / 32.f) - mu * mu;
      float r = rsqrtf(var + 1e-5f);
      if (lane < 32) A[lane] = (a - mu) * r * g1[lane] + be1[lane];
    }
    __syncthreads();
    float o[2];
    lin_gn<64, 32>(lane, W2, b2, g2, be2, A, o);
    B[lane] = o[0];
    __syncthreads();
    lin_gn<128, 64>(lane, W3, b3, g3, be3, B, o);
    A[lane] = o[0]; A[64 + lane] = o[1];
    fOut[(size_t)p * 128 + lane] = o[0];
    fOut[(size_t)p * 128 + 64 + lane] = o[1];
    __syncthreads();
    lin_gn<128, 128>(lane, W4, b4, g4, be4, A, o);
    cm0 = fmaxf(cm0, o[0]); cm1 = fmaxf(cm1, o[1]);
    __syncthreads();
  }
  cms[wave][lane] = cm0; cms[wave][64 + lane] = cm1;
  __syncthreads();
  if (threadIdx.x < 128) {
    float m0 = fmaxf(fmaxf(cms[0][threadIdx.x], cms[1][threadIdx.x]),
                     fmaxf(cms[2][threadIdx.x], cms[3][threadIdx.x]));
    atomicMax(&gMax[threadIdx.x], fenc(m0));
  }
}

// --------------------- layers 5-7 + row normalize --------------------------
__global__ __launch_bounds__(256) void k_mlp57(
    const float* __restrict__ f, const unsigned* __restrict__ gMax, int n,
    const float* __restrict__ W5, const float* __restrict__ b5, const float* __restrict__ g5, const float* __restrict__ be5,
    const float* __restrict__ W6, const float* __restrict__ b6, const float* __restrict__ g6, const float* __restrict__ be6,
    const float* __restrict__ W7, const float* __restrict__ b7,
    float* __restrict__ ovOut)
{
  __shared__ float bufA[WPB][256];
  __shared__ float bufB[WPB][256];
  const int wave = threadIdx.x >> 6, lane = threadIdx.x & 63;
  float* A = bufA[wave];
  float* B = bufB[wave];
  A[128 + lane] = fdec(gMax[lane]);          // g part of fg, constant per launch
  A[192 + lane] = fdec(gMax[64 + lane]);
  __syncthreads();
  const int gw = blockIdx.x * WPB + wave;
  const int nw = gridDim.x * WPB;
  for (int p = gw; p < n; p += nw) {
    A[lane] = f[(size_t)p * 128 + lane];
    A[64 + lane] = f[(size_t)p * 128 + 64 + lane];
    __syncthreads();
    float o[2];
    lin_gn<128, 256>(lane, W5, b5, g5, be5, A, o);
    B[lane] = o[0]; B[64 + lane] = o[1];
    __syncthreads();
    lin_gn<64, 128>(lane, W6, b6, g6, be6, B, o);
    B[128 + lane] = o[0];
    __syncthreads();
    // layer7: plain linear 64->128
    float acc0 = b7[lane], acc1 = b7[64 + lane];
    {
      const float4* in4 = reinterpret_cast<const float4*>(B + 128);
      const float4* w40 = reinterpret_cast<const float4*>(W7 + (size_t)lane * 64);
      const float4* w41 = reinterpret_cast<const float4*>(W7 + (size_t)(64 + lane) * 64);
#pragma unroll
      for (int k = 0; k < 16; ++k) {
        float4 v = in4[k];
        float4 w = w40[k];
        acc0 += w.x * v.x + w.y * v.y + w.z * v.z + w.w * v.w;
        w = w41[k];
        acc1 += w.x * v.x + w.y * v.y + w.z * v.z + w.w * v.w;
      }
    }
    float ss = rsum64(acc0 * acc0 + acc1 * acc1);
    float inv = 1.0f / sqrtf(ss);
    ovOut[(size_t)p * 128 + lane] = acc0 * inv;
    ovOut[(size_t)p * 128 + 64 + lane] = acc1 * inv;
    __syncthreads();
  }
}

// ---------------- fused sMat = ov @ op.T + row argmax ----------------------
// block: 64 ov-rows x 64 op-cols tile, 256 threads = 16(row)x16(col),
// 4x4 register micro-tile. j-range split into `chunks`, merged via packed
// atomicMax (fenc(val)<<32 | ~idx) -> value-desc, idx-asc (first-max) order.
__global__ __launch_bounds__(256) void k_argmax(
    const float* __restrict__ ov, const float* __restrict__ op,
    int m, int chunks,
    unsigned long long* __restrict__ best)
{
  __shared__ float As[64][128];   // row-major   (32 KB)
  __shared__ float Bs[128][64];   // k-major     (32 KB)
  const int tid = threadIdx.x;
  const int tc = tid & 15, tr = tid >> 4;
  const int rowBlock = blockIdx.x / chunks;
  const int chunk = blockIdx.x % chunks;
  const int row0 = rowBlock * 64;
  const int jspan = m / chunks;
  const int j0beg = chunk * jspan;

  {  // stage A once per block (coalesced float4 copy)
    const float4* src = reinterpret_cast<const float4*>(ov + (size_t)row0 * 128);
    float4* dst = reinterpret_cast<float4*>(&As[0][0]);
#pragma unroll
    for (int i = 0; i < 8; ++i) dst[tid + 256 * i] = src[tid + 256 * i];
  }

  float rmax[4]; int ridx[4];
#pragma unroll
  for (int r = 0; r < 4; ++r) { rmax[r] = -3.4e38f; ridx[r] = 0; }

  for (int j0 = j0beg; j0 < j0beg + jspan; j0 += 64) {
    __syncthreads();
#pragma unroll
    for (int i = 0; i < 8; ++i) {    // stage B transposed (k-major)
      int lin = tid + 256 * i;
      int j = lin >> 5, kq = lin & 31;
      float4 v = *reinterpret_cast<const float4*>(op + (size_t)(j0 + j) * 128 + kq * 4);
      Bs[kq * 4 + 0][j] = v.x;
      Bs[kq * 4 + 1][j] = v.y;
      Bs[kq * 4 + 2][j] = v.z;
      Bs[kq * 4 + 3][j] = v.w;
    }
    __syncthreads();
    float s[4][4];
#pragma unroll
    for (int r = 0; r < 4; ++r) { s[r][0] = 0.f; s[r][1] = 0.f; s[r][2] = 0.f; s[r][3] = 0.f; }
#pragma unroll 2
    for (int k = 0; k < 128; k += 4) {
      float a[4][4], bb[4][4];
#pragma unroll
      for (int r = 0; r < 4; ++r)
        *reinterpret_cast<float4*>(&a[r][0]) = *reinterpret_cast<const float4*>(&As[tr * 4 + r][k]);
#pragma unroll
      for (int kk = 0; kk < 4; ++kk)
        *reinterpret_cast<float4*>(&bb[kk][0]) = *reinterpret_cast<const float4*>(&Bs[k + kk][tc * 4]);
#pragma unroll
      for (int r = 0; r < 4; ++r)
#pragma unroll
        for (int kk = 0; kk < 4; ++kk)
#pragma unroll
          for (int c = 0; c < 4; ++c)
            s[r][c] += a[r][kk] * bb[kk][c];
    }
#pragma unroll
    for (int r = 0; r < 4; ++r)
#pragma unroll
      for (int c = 0; c < 4; ++c) {
        float v = s[r][c];
        int j = j0 + tc * 4 + c;
        if (v > rmax[r]) { rmax[r] = v; ridx[r] = j; }   // strict > keeps first max
      }
  }
  // reduce across the 16 col-threads (consecutive lanes within a wave)
#pragma unroll
  for (int mm = 1; mm <= 8; mm <<= 1) {
#pragma unroll
    for (int r = 0; r < 4; ++r) {
      float vv = __shfl_xor(rmax[r], mm);
      int jj = __shfl_xor(ridx[r], mm);
      if (vv > rmax[r] || (vv == rmax[r] && jj < ridx[r])) { rmax[r] = vv; ridx[r] = jj; }
    }
  }
  if (tc == 0) {
#pragma unroll
    for (int r = 0; r < 4; ++r) {
      unsigned long long pk =
          ((unsigned long long)fenc(rmax[r]) << 32) |
          (unsigned long long)(0xFFFFFFFFu - (unsigned)ridx[r]);
      atomicMax(&best[row0 + tr * 4 + r], pk);
    }
  }
}

// ----------------------- gather + layer8 + W9 ------------------------------
__global__ __launch_bounds__(256) void k_oc(
    const float* __restrict__ ovn, const float* __restrict__ opn,
    const unsigned long long* __restrict__ best, int n,
    const float* __restrict__ W8, const float* __restrict__ b8,
    const float* __restrict__ g8, const float* __restrict__ be8,
    const float* __restrict__ W9, const float* __restrict__ b9,
    float* __restrict__ oc)
{
  __shared__ float buf[WPB][260];
  const int wave = threadIdx.x >> 6, lane = threadIdx.x & 63;
  float* A = buf[wave];
  const int gw = blockIdx.x * WPB + wave;
  const int nw = gridDim.x * WPB;
  for (int p = gw; p < n; p += nw) {
    unsigned long long v = best[p];
    int j = (int)(0xFFFFFFFFu - (unsigned)(v & 0xFFFFFFFFu));
    float Sv = fdec((unsigned)(v >> 32));
    A[lane]       = ovn[(size_t)p * 128 + lane];
    A[64 + lane]  = ovn[(size_t)p * 128 + 64 + lane];
    A[128 + lane] = opn[(size_t)j * 128 + lane];
    A[192 + lane] = opn[(size_t)j * 128 + 64 + lane];
    if (lane == 0) A[256] = Sv;
    __syncthreads();
    // layer8: 257 -> 64, LeakyReLU, GN groups=2 (32-ch groups)
    float a = b8[lane];
    const float* w = W8 + (size_t)lane * 257;
#pragma unroll 8
    for (int k = 0; k < 256; k += 4)
      a += w[k] * A[k] + w[k + 1] * A[k + 1] + w[k + 2] * A[k + 2] + w[k + 3] * A[k + 3];
    a += w[256] * A[256];
    a = a >= 0.f ? a : 0.2f * a;
    float s1 = rsum32(a), s2 = rsum32(a * a);
    float mu = s1 * (1.f / 32.f);
    float var = s2 * (1.f / 32.f) - mu * mu;
    float r = rsqrtf(var + 1e-5f);
    float y = (a - mu) * r * g8[lane] + be8[lane];
    float tot = rsum64(y * W9[lane]);
    if (lane == 0) oc[p] = tot + b9[0];
    __syncthreads();
  }
}

// ---------------------------------------------------------------------------
extern "C" void kernel_launch(void* const* d_in, const int* in_sizes, int n_in,
                              void* d_out, int out_size, void* d_ws, size_t ws_size,
                              hipStream_t stream)
{
  (void)n_in; (void)out_size; (void)ws_size;
  const float* vtx = (const float*)d_in[0];
  const float* pts = (const float*)d_in[1];
  const float* W1 = (const float*)d_in[2];  const float* b1 = (const float*)d_in[3];
  const float* g1 = (const float*)d_in[4];  const float* be1 = (const float*)d_in[5];
  const float* W2 = (const float*)d_in[6];  const float* b2 = (const float*)d_in[7];
  const float* g2 = (const float*)d_in[8];  const float* be2 = (const float*)d_in[9];
  const float* W3 = (const float*)d_in[10]; const float* b3 = (const float*)d_in[11];
  const float* g3 = (const float*)d_in[12]; const float* be3 = (const float*)d_in[13];
  const float* W4 = (const float*)d_in[14]; const float* b4 = (const float*)d_in[15];
  const float* g4 = (const float*)d_in[16]; const float* be4 = (const float*)d_in[17];
  const float* W5 = (const float*)d_in[18]; const float* b5 = (const float*)d_in[19];
  const float* g5 = (const float*)d_in[20]; const float* be5 = (const float*)d_in[21];
  const float* W6 = (const float*)d_in[22]; const float* b6 = (const float*)d_in[23];
  const float* g6 = (const float*)d_in[24]; const float* be6 = (const float*)d_in[25];
  const float* W7 = (const float*)d_in[26]; const float* b7 = (const float*)d_in[27];
  const float* W8 = (const float*)d_in[28]; const float* b8 = (const float*)d_in[29];
  const float* g8 = (const float*)d_in[30]; const float* be8 = (const float*)d_in[31];
  const float* W9 = (const float*)d_in[32]; const float* b9 = (const float*)d_in[33];

  const int n = in_sizes[0] / 3;   // 16384
  const int m = in_sizes[1] / 3;   // 16384

  // workspace layout (fp32 elements)
  float* ws = (float*)d_ws;
  float* f_v = ws;                                   // n*128
  float* f_p = ws + (size_t)n * 128;                 // m*128
  unsigned* g_v = (unsigned*)(ws + (size_t)(n + m) * 128);  // 128
  unsigned* g_p = g_v + 128;                               // 128
  unsigned long long* best = (unsigned long long*)(g_p + 128);  // n (8B aligned)

  float* out_ov = (float*)d_out;                 // n*128
  float* out_op = out_ov + (size_t)n * 128;      // m*128
  float* out_oc = out_op + (size_t)m * 128;      // n

  k_init<<<64, 256, 0, stream>>>(g_v, g_p, best, n);

  k_mlp14<<<1024, 256, 0, stream>>>(vtx, n, W1, b1, g1, be1, W2, b2, g2, be2,
                                    W3, b3, g3, be3, W4, b4, g4, be4, f_v, g_v);
  k_mlp14<<<1024, 256, 0, stream>>>(pts, m, W1, b1, g1, be1, W2, b2, g2, be2,
                                    W3, b3, g3, be3, W4, b4, g4, be4, f_p, g_p);

  k_mlp57<<<1024, 256, 0, stream>>>(f_v, g_v, n, W5, b5, g5, be5,
                                    W6, b6, g6, be6, W7, b7, out_ov);
  k_mlp57<<<1024, 256, 0, stream>>>(f_p, g_p, m, W5, b5, g5, be5,
                                    W6, b6, g6, be6, W7, b7, out_op);

  const int chunks = 4;                       // j-range split for occupancy
  k_argmax<<<(n / 64) * chunks, 256, 0, stream>>>(out_ov, out_op, m, chunks, best);

  k_oc<<<1024, 256, 0, stream>>>(out_ov, out_op, best, n,
                                 W8, b8, g8, be8, W9, b9, out_oc);
}

// Round 5
// 2496.444 us; speedup vs baseline: 1.3979x; 1.3979x over previous
//
#include <hip/hip_runtime.h>
#include <hip/hip_bf16.h>
#include <math.h>

// ---------------------------------------------------------------------------
// CorrNet forward, MI355X. Round 5 (= round 4 resubmit; broker timeout).
// Pipeline:
//   k_init     : zero global-max + packed-argmax + row-max scratch
//   k_mlp14    : layers 1-4, writes f[n,128], atomicMax col-max g[128]
//   k_mlp57    : layers 5-7 + row L2-normalize -> ov/op (fp32 out) +
//                planar bf16 hi/lo copies for the MFMA passes
//   k_amax<1>  : 3-pass bf16 MFMA GEMM, per-row approx max value only
//   k_amax<2>  : same GEMM; entries within delta of row max get an EXACT
//                fp32 dot re-eval + packed (val,idx) atomicMax commit
//   k_oc       : gather X=op[idx], layer8 + W9 -> oc
// Round-3 failure was ~4e-6 approx error flipping near-tie argmax indices;
// pass 2's exact re-eval restores fp32-argmax semantics at MFMA speed.
// ---------------------------------------------------------------------------

#define WPB 4        // waves per block for the MLP kernels
#define AM_CHUNKS 4  // j-range split of the argmax GEMM
#define AM_DELTA 2e-4f  // candidate margin (>> 3-pass error bound ~4e-6)

typedef unsigned short ushort_t;
typedef __attribute__((ext_vector_type(8))) short short8v;   // 8 bf16 = 4 VGPR
typedef __attribute__((ext_vector_type(16))) float f32x16;   // MFMA 32x32 acc

__device__ __forceinline__ float rsum32(float v) {
  v += __shfl_xor(v, 1);
  v += __shfl_xor(v, 2);
  v += __shfl_xor(v, 4);
  v += __shfl_xor(v, 8);
  v += __shfl_xor(v, 16);
  return v;
}
__device__ __forceinline__ float rsum64(float v) {
  v = rsum32(v);
  v += __shfl_xor(v, 32);
  return v;
}

// order-preserving float<->uint encoding (monotonic for all finite values)
__device__ __forceinline__ unsigned fenc(float f) {
  unsigned u = __float_as_uint(f);
  return (u & 0x80000000u) ? ~u : (u | 0x80000000u);
}
__device__ __forceinline__ float fdec(unsigned k) {
  return __uint_as_float((k & 0x80000000u) ? (k ^ 0x80000000u) : ~k);
}

// float -> bf16 bits (round-to-nearest-even), and back
__device__ __forceinline__ ushort_t f2bf(float f) {
  unsigned u = __float_as_uint(f);
  return (ushort_t)((u + 0x7FFFu + ((u >> 16) & 1u)) >> 16);
}
__device__ __forceinline__ float bf2f(ushort_t h) {
  return __uint_as_float(((unsigned)h) << 16);
}

// exact fp32 dot (sequential adds, round-1-equivalent ordering) + commit
__device__ __noinline__ void exact_commit(const float* __restrict__ a,
                                          const float* __restrict__ b,
                                          int j, unsigned long long* slot)
{
  const float4* a4 = (const float4*)a;
  const float4* b4 = (const float4*)b;
  float s = 0.f;
#pragma unroll 4
  for (int k = 0; k < 32; ++k) {
    float4 x = a4[k], y = b4[k];
    s += x.x * y.x; s += x.y * y.y; s += x.z * y.z; s += x.w * y.w;
  }
  unsigned long long pk = ((unsigned long long)fenc(s) << 32)
                        | (unsigned long long)(0xFFFFFFFFu - (unsigned)j);
  atomicMax(slot, pk);
}

// Linear (x @ W.T + b) -> LeakyReLU(0.2) -> GroupNorm(32-channel groups).
template<int OUT_C, int IN_C>
__device__ __forceinline__ void lin_gn(int lane,
    const float* __restrict__ W, const float* __restrict__ b,
    const float* __restrict__ gm, const float* __restrict__ be,
    const float* __restrict__ in, float out[2])
{
  constexpr int J = (OUT_C + 63) / 64;
  const float4* in4 = reinterpret_cast<const float4*>(in);
  float acc[J];
  const float4* w4[J];
#pragma unroll
  for (int j = 0; j < J; ++j) {
    acc[j] = b[lane + 64 * j];
    w4[j] = reinterpret_cast<const float4*>(W + (size_t)(lane + 64 * j) * IN_C);
  }
#pragma unroll
  for (int k = 0; k < IN_C / 4; ++k) {
    float4 v = in4[k];
#pragma unroll
    for (int j = 0; j < J; ++j) {
      float4 w = w4[j][k];
      acc[j] += w.x * v.x + w.y * v.y + w.z * v.z + w.w * v.w;
    }
  }
#pragma unroll
  for (int j = 0; j < J; ++j) {
    const int c = lane + 64 * j;
    float a = acc[j];
    a = a >= 0.f ? a : 0.2f * a;            // LeakyReLU(0.2)
    float s1 = rsum32(a);                    // group = 32 consecutive channels
    float s2 = rsum32(a * a);
    float mu = s1 * (1.f / 32.f);
    float var = s2 * (1.f / 32.f) - mu * mu;
    float r = rsqrtf(var + 1e-5f);
    out[j] = (a - mu) * r * gm[c] + be[c];
  }
}

// -------------------------------- init -------------------------------------
__global__ void k_init(unsigned* __restrict__ gv, unsigned* __restrict__ gp,
                       unsigned long long* __restrict__ best,
                       unsigned* __restrict__ rmax, int n)
{
  int i = blockIdx.x * blockDim.x + threadIdx.x;
  if (i < 128) { gv[i] = 0u; gp[i] = 0u; }     // fenc floor (= -inf)
  for (int k = i; k < n; k += gridDim.x * blockDim.x) {
    best[k] = 0ull;
    rmax[k] = 0u;
  }
}

// ------------------------- layers 1-4 + col-max ----------------------------
__global__ __launch_bounds__(256) void k_mlp14(
    const float* __restrict__ x, int n,
    const float* __restrict__ W1, const float* __restrict__ b1, const float* __restrict__ g1, const float* __restrict__ be1,
    const float* __restrict__ W2, const float* __restrict__ b2, const float* __restrict__ g2, const float* __restrict__ be2,
    const float* __restrict__ W3, const float* __restrict__ b3, const float* __restrict__ g3, const float* __restrict__ be3,
    const float* __restrict__ W4, const float* __restrict__ b4, const float* __restrict__ g4, const float* __restrict__ be4,
    float* __restrict__ fOut, unsigned* __restrict__ gMax)
{
  __shared__ float buf[WPB][2][128];
  __shared__ float cms[WPB][128];
  const int wave = threadIdx.x >> 6, lane = threadIdx.x & 63;
  float* A = buf[wave][0];
  float* B = buf[wave][1];
  float cm0 = -3.4e38f, cm1 = -3.4e38f;
  const int gw = blockIdx.x * WPB + wave;
  const int nw = gridDim.x * WPB;
  for (int p = gw; p < n; p += nw) {
    const float x0 = x[3 * p], x1 = x[3 * p + 1], x2 = x[3 * p + 2];
    {   // layer1: 3->32, groups=1 (32-ch group)
      float a = 0.f;
      if (lane < 32)
        a = b1[lane] + W1[lane * 3] * x0 + W1[lane * 3 + 1] * x1 + W1[lane * 3 + 2] * x2;
      a = a >= 0.f ? a : 0.2f * a;
      float s1 = rsum32(a), s2 = rsum32(a * a);
      float mu = s1 * (1.f / 32.f);
      float var = s2 * (1.f / 32.f) - mu * mu;
      float r = rsqrtf(var + 1e-5f);
      if (lane < 32) A[lane] = (a - mu) * r * g1[lane] + be1[lane];
    }
    __syncthreads();
    float o[2];
    lin_gn<64, 32>(lane, W2, b2, g2, be2, A, o);
    B[lane] = o[0];
    __syncthreads();
    lin_gn<128, 64>(lane, W3, b3, g3, be3, B, o);
    A[lane] = o[0]; A[64 + lane] = o[1];
    fOut[(size_t)p * 128 + lane] = o[0];
    fOut[(size_t)p * 128 + 64 + lane] = o[1];
    __syncthreads();
    lin_gn<128, 128>(lane, W4, b4, g4, be4, A, o);
    cm0 = fmaxf(cm0, o[0]); cm1 = fmaxf(cm1, o[1]);
    __syncthreads();
  }
  cms[wave][lane] = cm0; cms[wave][64 + lane] = cm1;
  __syncthreads();
  if (threadIdx.x < 128) {
    float m0 = fmaxf(fmaxf(cms[0][threadIdx.x], cms[1][threadIdx.x]),
                     fmaxf(cms[2][threadIdx.x], cms[3][threadIdx.x]));
    atomicMax(&gMax[threadIdx.x], fenc(m0));
  }
}

// --------------------- layers 5-7 + row normalize + bf16 split -------------
__global__ __launch_bounds__(256) void k_mlp57(
    const float* __restrict__ f, const unsigned* __restrict__ gMax, int n,
    const float* __restrict__ W5, const float* __restrict__ b5, const float* __restrict__ g5, const float* __restrict__ be5,
    const float* __restrict__ W6, const float* __restrict__ b6, const float* __restrict__ g6, const float* __restrict__ be6,
    const float* __restrict__ W7, const float* __restrict__ b7,
    float* __restrict__ ovOut,
    ushort_t* __restrict__ ovH, ushort_t* __restrict__ ovL)
{
  __shared__ float bufA[WPB][256];
  __shared__ float bufB[WPB][256];
  const int wave = threadIdx.x >> 6, lane = threadIdx.x & 63;
  float* A = bufA[wave];
  float* B = bufB[wave];
  A[128 + lane] = fdec(gMax[lane]);          // g part of fg, constant per launch
  A[192 + lane] = fdec(gMax[64 + lane]);
  __syncthreads();
  const int gw = blockIdx.x * WPB + wave;
  const int nw = gridDim.x * WPB;
  for (int p = gw; p < n; p += nw) {
    A[lane] = f[(size_t)p * 128 + lane];
    A[64 + lane] = f[(size_t)p * 128 + 64 + lane];
    __syncthreads();
    float o[2];
    lin_gn<128, 256>(lane, W5, b5, g5, be5, A, o);
    B[lane] = o[0]; B[64 + lane] = o[1];
    __syncthreads();
    lin_gn<64, 128>(lane, W6, b6, g6, be6, B, o);
    B[128 + lane] = o[0];
    __syncthreads();
    // layer7: plain linear 64->128
    float acc0 = b7[lane], acc1 = b7[64 + lane];
    {
      const float4* in4 = reinterpret_cast<const float4*>(B + 128);
      const float4* w40 = reinterpret_cast<const float4*>(W7 + (size_t)lane * 64);
      const float4* w41 = reinterpret_cast<const float4*>(W7 + (size_t)(64 + lane) * 64);
#pragma unroll
      for (int k = 0; k < 16; ++k) {
        float4 v = in4[k];
        float4 w = w40[k];
        acc0 += w.x * v.x + w.y * v.y + w.z * v.z + w.w * v.w;
        w = w41[k];
        acc1 += w.x * v.x + w.y * v.y + w.z * v.z + w.w * v.w;
      }
    }
    float ss = rsum64(acc0 * acc0 + acc1 * acc1);
    float inv = 1.0f / sqrtf(ss);
    float v0 = acc0 * inv, v1 = acc1 * inv;
    ovOut[(size_t)p * 128 + lane] = v0;
    ovOut[(size_t)p * 128 + 64 + lane] = v1;
    // bf16 hi/lo split for the MFMA passes
    ushort_t h0 = f2bf(v0), h1 = f2bf(v1);
    ovH[(size_t)p * 128 + lane] = h0;
    ovH[(size_t)p * 128 + 64 + lane] = h1;
    ovL[(size_t)p * 128 + lane] = f2bf(v0 - bf2f(h0));
    ovL[(size_t)p * 128 + 64 + lane] = f2bf(v1 - bf2f(h1));
    __syncthreads();
  }
}

// ---------------- two-phase fused ov@op.T + row argmax (MFMA) --------------
// Block: 128 ov-rows (4 waves x 32) x 64 op-cols per iteration.
// 3-pass bf16 split: s = ahi.bhi + ahi.blo + alo.bhi  (error <~ 4e-6).
// PASS 1: per-row approx max value -> rowmax (fenc atomicMax).
// PASS 2: entries with c >= rowmax - AM_DELTA get exact fp32 re-eval +
//         packed (fenc(exact)<<32 | ~idx) atomicMax -> fp32-argmax semantics.
// C layout (verified): col = lane&31, row = (reg&3)+8*(reg>>2)+4*(lane>>5).
template<int PASS>
__global__ __launch_bounds__(256) void k_amax(
    const ushort_t* __restrict__ avh, const ushort_t* __restrict__ avl,
    const ushort_t* __restrict__ bvh, const ushort_t* __restrict__ bvl,
    const float* __restrict__ ovf, const float* __restrict__ opf,
    int m, unsigned* __restrict__ rowmax, unsigned long long* __restrict__ best)
{
  // [hi/lo][k-chunk 16][col pad 65][8 bf16] = 32.5 KB; 16B-aligned for b128
  __shared__ __align__(16) short lbuf[2][16][65][8];
  const int tid = threadIdx.x;
  const int wave = tid >> 6, lane = tid & 63;
  const int l31 = lane & 31, grp = lane >> 5;
  const int rowBlock = blockIdx.x / AM_CHUNKS;
  const int chunk = blockIdx.x % AM_CHUNKS;
  const int row0 = rowBlock * 128;
  const int jspan = m / AM_CHUNKS;
  const int j0beg = chunk * jspan;
  const int iters = jspan / 64;

  // ---- A fragments, once per block: row = row0 + wave*32 + (lane&31) ----
  const int myrow = row0 + wave * 32 + l31;
  short8v ah[8], al[8];
  {
    const short8v* rh = (const short8v*)(avh + (size_t)myrow * 128);
    const short8v* rl = (const short8v*)(avl + (size_t)myrow * 128);
#pragma unroll
    for (int ks = 0; ks < 8; ++ks) {
      ah[ks] = rh[ks * 2 + grp];        // k = ks*16 + grp*8 + [0..7]
      al[ks] = rl[ks * 2 + grp];
    }
  }

  // staging mapping: thread t loads row j0+(t>>4)+16i, bytes (t&15)*16 (coalesced)
  const int sks = tid & 15;
  const int scol0 = tid >> 4;
  // per-lane LDS fragment base, in 16B units: [grp][l31]
  const short8v* fragH = (const short8v*)&lbuf[0][grp][l31][0];
  const short8v* fragL = (const short8v*)&lbuf[1][grp][l31][0];

  // pass-1 state: running per-row approx max.  pass-2 state: thresholds.
  float rmx[16];
  float thr[16];
#pragma unroll
  for (int r = 0; r < 16; ++r) {
    if constexpr (PASS == 1) {
      rmx[r] = -3.4e38f;
    } else {
      const int row = row0 + wave * 32 + (r & 3) + 8 * (r >> 2) + 4 * grp;
      thr[r] = fdec(rowmax[row]) - AM_DELTA;   // wave-uniform load, broadcast
    }
  }

  // prologue loads (tile 0)
  short8v ph[4], pl[4];
#pragma unroll
  for (int i = 0; i < 4; ++i) {
    int col = scol0 + 16 * i;
    ph[i] = ((const short8v*)bvh)[(size_t)(j0beg + col) * 16 + sks];
    pl[i] = ((const short8v*)bvl)[(size_t)(j0beg + col) * 16 + sks];
  }

  for (int it = 0; it < iters; ++it) {
    __syncthreads();                               // LDS free (prev tile consumed)
#pragma unroll
    for (int i = 0; i < 4; ++i) {
      int col = scol0 + 16 * i;
      *(short8v*)&lbuf[0][sks][col][0] = ph[i];
      *(short8v*)&lbuf[1][sks][col][0] = pl[i];
    }
    __syncthreads();
    if (it + 1 < iters) {                          // prefetch next tile -> regs,
      int j0n = j0beg + (it + 1) * 64;             // overlaps with MFMA below
#pragma unroll
      for (int i = 0; i < 4; ++i) {
        int col = scol0 + 16 * i;
        ph[i] = ((const short8v*)bvh)[(size_t)(j0n + col) * 16 + sks];
        pl[i] = ((const short8v*)bvl)[(size_t)(j0n + col) * 16 + sks];
      }
    }
    const int j0 = j0beg + it * 64;
#pragma unroll
    for (int ct = 0; ct < 2; ++ct) {
      f32x16 c = {};
#pragma unroll
      for (int ks = 0; ks < 8; ++ks) {
        short8v bh = fragH[ks * 130 + ct * 32];    // (ks*2+grp)*65 + l31 + 32ct
        short8v bl = fragL[ks * 130 + ct * 32];
        c = __builtin_amdgcn_mfma_f32_32x32x16_bf16(ah[ks], bh, c, 0, 0, 0);
        c = __builtin_amdgcn_mfma_f32_32x32x16_bf16(ah[ks], bl, c, 0, 0, 0);
        c = __builtin_amdgcn_mfma_f32_32x32x16_bf16(al[ks], bh, c, 0, 0, 0);
      }
      if constexpr (PASS == 1) {
#pragma unroll
        for (int r = 0; r < 16; ++r) rmx[r] = fmaxf(rmx[r], c[r]);
      } else {
        const int j = j0 + ct * 32 + l31;          // this lane's column
        bool any = false;
#pragma unroll
        for (int r = 0; r < 16; ++r) any = any || (c[r] >= thr[r]);
        if (__any((int)any)) {                     // rare: exact re-eval path
#pragma unroll
          for (int r = 0; r < 16; ++r) {
            if (c[r] >= thr[r]) {
              const int row = row0 + wave * 32 + (r & 3) + 8 * (r >> 2) + 4 * grp;
              exact_commit(ovf + (size_t)row * 128, opf + (size_t)j * 128,
                           j, &best[row]);
            }
          }
        }
      }
    }
  }

  if constexpr (PASS == 1) {
    // butterfly fmax across the 32 column-lanes, then one atomic per row
#pragma unroll
    for (int mm = 1; mm <= 16; mm <<= 1) {
#pragma unroll
      for (int r = 0; r < 16; ++r) rmx[r] = fmaxf(rmx[r], __shfl_xor(rmx[r], mm));
    }
    if (l31 == 0) {
#pragma unroll
      for (int r = 0; r < 16; ++r) {
        const int row = row0 + wave * 32 + (r & 3) + 8 * (r >> 2) + 4 * grp;
        atomicMax(&rowmax[row], fenc(rmx[r]));
      }
    }
  }
}

// ----------------------- gather + layer8 + W9 ------------------------------
__global__ __launch_bounds__(256) void k_oc(
    const float* __restrict__ ovn, const float* __restrict__ opn,
    const unsigned long long* __restrict__ best, int n,
    const float* __restrict__ W8, const float* __restrict__ b8,
    const float* __restrict__ g8, const float* __restrict__ be8,
    const float* __restrict__ W9, const float* __restrict__ b9,
    float* __restrict__ oc)
{
  __shared__ float buf[WPB][260];
  const int wave = threadIdx.x >> 6, lane = threadIdx.x & 63;
  float* A = buf[wave];
  const int gw = blockIdx.x * WPB + wave;
  const int nw = gridDim.x * WPB;
  for (int p = gw; p < n; p += nw) {
    unsigned long long v = best[p];
    int j = (int)(0xFFFFFFFFu - (unsigned)(v & 0xFFFFFFFFu));
    float Sv = fdec((unsigned)(v >> 32));
    A[lane]       = ovn[(size_t)p * 128 + lane];
    A[64 + lane]  = ovn[(size_t)p * 128 + 64 + lane];
    A[128 + lane] = opn[(size_t)j * 128 + lane];
    A[192 + lane] = opn[(size_t)j * 128 + 64 + lane];
    if (lane == 0) A[256] = Sv;
    __syncthreads();
    // layer8: 257 -> 64, LeakyReLU, GN groups=2 (32-ch groups)
    float a = b8[lane];
    const float* w = W8 + (size_t)lane * 257;
#pragma unroll 8
    for (int k = 0; k < 256; k += 4)
      a += w[k] * A[k] + w[k + 1] * A[k + 1] + w[k + 2] * A[k + 2] + w[k + 3] * A[k + 3];
    a += w[256] * A[256];
    a = a >= 0.f ? a : 0.2f * a;
    float s1 = rsum32(a), s2 = rsum32(a * a);
    float mu = s1 * (1.f / 32.f);
    float var = s2 * (1.f / 32.f) - mu * mu;
    float r = rsqrtf(var + 1e-5f);
    float y = (a - mu) * r * g8[lane] + be8[lane];
    float tot = rsum64(y * W9[lane]);
    if (lane == 0) oc[p] = tot + b9[0];
    __syncthreads();
  }
}

// ---------------------------------------------------------------------------
extern "C" void kernel_launch(void* const* d_in, const int* in_sizes, int n_in,
                              void* d_out, int out_size, void* d_ws, size_t ws_size,
                              hipStream_t stream)
{
  (void)n_in; (void)out_size; (void)ws_size;
  const float* vtx = (const float*)d_in[0];
  const float* pts = (const float*)d_in[1];
  const float* W1 = (const float*)d_in[2];  const float* b1 = (const float*)d_in[3];
  const float* g1 = (const float*)d_in[4];  const float* be1 = (const float*)d_in[5];
  const float* W2 = (const float*)d_in[6];  const float* b2 = (const float*)d_in[7];
  const float* g2 = (const float*)d_in[8];  const float* be2 = (const float*)d_in[9];
  const float* W3 = (const float*)d_in[10]; const float* b3 = (const float*)d_in[11];
  const float* g3 = (const float*)d_in[12]; const float* be3 = (const float*)d_in[13];
  const float* W4 = (const float*)d_in[14]; const float* b4 = (const float*)d_in[15];
  const float* g4 = (const float*)d_in[16]; const float* be4 = (const float*)d_in[17];
  const float* W5 = (const float*)d_in[18]; const float* b5 = (const float*)d_in[19];
  const float* g5 = (const float*)d_in[20]; const float* be5 = (const float*)d_in[21];
  const float* W6 = (const float*)d_in[22]; const float* b6 = (const float*)d_in[23];
  const float* g6 = (const float*)d_in[24]; const float* be6 = (const float*)d_in[25];
  const float* W7 = (const float*)d_in[26]; const float* b7 = (const float*)d_in[27];
  const float* W8 = (const float*)d_in[28]; const float* b8 = (const float*)d_in[29];
  const float* g8 = (const float*)d_in[30]; const float* be8 = (const float*)d_in[31];
  const float* W9 = (const float*)d_in[32]; const float* b9 = (const float*)d_in[33];

  const int n = in_sizes[0] / 3;   // 16384
  const int m = in_sizes[1] / 3;   // 16384

  // ---- workspace layout (bytes) ----
  // f_v   @ 0              n*128*4
  // f_p   @ f_v_end        m*128*4   (ovh/ovl alias f_p once it is consumed)
  // oph   @ f_p_end        m*128*2
  // opl   @ oph_end        m*128*2
  // g_v/g_p, best[n] u64, rmax[n] u32 after that
  char* wsb = (char*)d_ws;
  float* f_v = (float*)wsb;
  size_t f_v_bytes = (size_t)n * 128 * 4;
  float* f_p = (float*)(wsb + f_v_bytes);
  size_t f_p_bytes = (size_t)m * 128 * 4;
  ushort_t* ovh = (ushort_t*)(wsb + f_v_bytes);                       // alias f_p
  ushort_t* ovl = (ushort_t*)(wsb + f_v_bytes + (size_t)n * 128 * 2); // alias f_p
  ushort_t* oph = (ushort_t*)(wsb + f_v_bytes + f_p_bytes);
  ushort_t* opl = (ushort_t*)(wsb + f_v_bytes + f_p_bytes + (size_t)m * 128 * 2);
  char* tail = wsb + f_v_bytes + f_p_bytes + (size_t)m * 128 * 4;
  unsigned* g_v = (unsigned*)tail;
  unsigned* g_p = g_v + 128;
  unsigned long long* best = (unsigned long long*)(g_p + 128);  // 8B aligned
  unsigned* rmaxv = (unsigned*)(best + n);

  float* out_ov = (float*)d_out;                 // n*128
  float* out_op = out_ov + (size_t)n * 128;      // m*128
  float* out_oc = out_op + (size_t)m * 128;      // n

  k_init<<<64, 256, 0, stream>>>(g_v, g_p, best, rmaxv, n);

  k_mlp14<<<1024, 256, 0, stream>>>(vtx, n, W1, b1, g1, be1, W2, b2, g2, be2,
                                    W3, b3, g3, be3, W4, b4, g4, be4, f_v, g_v);
  k_mlp14<<<1024, 256, 0, stream>>>(pts, m, W1, b1, g1, be1, W2, b2, g2, be2,
                                    W3, b3, g3, be3, W4, b4, g4, be4, f_p, g_p);

  // pts pass FIRST (f_p consumed), then vtx pass may overwrite f_p with ovh/ovl
  k_mlp57<<<1024, 256, 0, stream>>>(f_p, g_p, m, W5, b5, g5, be5,
                                    W6, b6, g6, be6, W7, b7, out_op, oph, opl);
  k_mlp57<<<1024, 256, 0, stream>>>(f_v, g_v, n, W5, b5, g5, be5,
                                    W6, b6, g6, be6, W7, b7, out_ov, ovh, ovl);

  const int am_grid = (n / 128) * AM_CHUNKS;
  k_amax<1><<<am_grid, 256, 0, stream>>>(ovh, ovl, oph, opl, out_ov, out_op,
                                         m, rmaxv, best);
  k_amax<2><<<am_grid, 256, 0, stream>>>(ovh, ovl, oph, opl, out_ov, out_op,
                                         m, rmaxv, best);

  k_oc<<<1024, 256, 0, stream>>>(out_ov, out_op, best, n,
                                 W8, b8, g8, be8, W9, b9, out_oc);
}

// Round 7
// 1096.211 us; speedup vs baseline: 3.1834x; 2.2773x over previous
//
#include <hip/hip_runtime.h>
#include <hip/hip_bf16.h>
#include <math.h>

// ---------------------------------------------------------------------------
// CorrNet forward, MI355X. Round 7 (= round 6 resubmit; broker timeout).
// Round-5 profile: k_mlp57 = 639us with 1.36 GB L2-miss traffic/dispatch --
// wave-per-point re-streamed 192 KB of weights per point. Fix: each wave
// processes PB=8 points; every weight float4 is loaded once and applied to
// 8 LDS-broadcast input vectors. Same accumulation order per point.
// Pipeline unchanged otherwise:
//   k_init / k_mlp14 / k_mlp57 / k_amax<1> / k_amax<2> / k_oc
// ---------------------------------------------------------------------------

#define WPB 4        // waves per block for the MLP kernels
#define PB 8         // points per wave (weight-reuse batch)
#define MLP_GRID 512 // 512 blocks x 4 waves = 2048 waves = 16384/PB batches
#define AM_CHUNKS 4  // j-range split of the argmax GEMM
#define AM_DELTA 2e-4f  // candidate margin (>> 3-pass error bound ~4e-6)

typedef unsigned short ushort_t;
typedef __attribute__((ext_vector_type(8))) short short8v;   // 8 bf16 = 4 VGPR
typedef __attribute__((ext_vector_type(16))) float f32x16;   // MFMA 32x32 acc

__device__ __forceinline__ float rsum32(float v) {
  v += __shfl_xor(v, 1);
  v += __shfl_xor(v, 2);
  v += __shfl_xor(v, 4);
  v += __shfl_xor(v, 8);
  v += __shfl_xor(v, 16);
  return v;
}
__device__ __forceinline__ float rsum64(float v) {
  v = rsum32(v);
  v += __shfl_xor(v, 32);
  return v;
}

// order-preserving float<->uint encoding (monotonic for all finite values)
__device__ __forceinline__ unsigned fenc(float f) {
  unsigned u = __float_as_uint(f);
  return (u & 0x80000000u) ? ~u : (u | 0x80000000u);
}
__device__ __forceinline__ float fdec(unsigned k) {
  return __uint_as_float((k & 0x80000000u) ? (k ^ 0x80000000u) : ~k);
}

// float -> bf16 bits (round-to-nearest-even), and back
__device__ __forceinline__ ushort_t f2bf(float f) {
  unsigned u = __float_as_uint(f);
  return (ushort_t)((u + 0x7FFFu + ((u >> 16) & 1u)) >> 16);
}
__device__ __forceinline__ float bf2f(ushort_t h) {
  return __uint_as_float(((unsigned)h) << 16);
}

// exact fp32 dot (sequential adds) + packed (val,idx) atomicMax commit
__device__ __noinline__ void exact_commit(const float* __restrict__ a,
                                          const float* __restrict__ b,
                                          int j, unsigned long long* slot)
{
  const float4* a4 = (const float4*)a;
  const float4* b4 = (const float4*)b;
  float s = 0.f;
#pragma unroll 4
  for (int k = 0; k < 32; ++k) {
    float4 x = a4[k], y = b4[k];
    s += x.x * y.x; s += x.y * y.y; s += x.z * y.z; s += x.w * y.w;
  }
  unsigned long long pk = ((unsigned long long)fenc(s) << 32)
                        | (unsigned long long)(0xFFFFFFFFu - (unsigned)j);
  atomicMax(slot, pk);
}

// Batched Linear (x @ W.T + b) -> LeakyReLU(0.2) -> GroupNorm(32-ch groups).
// `in` = LDS [PB][IN_C]; lane owns channel lane (+64). Each weight float4 is
// loaded once and applied to PB points (LDS broadcast reads, conflict-free).
template<int OUT_C, int IN_C>
__device__ __forceinline__ void lin_gn_b(int lane,
    const float* __restrict__ W, const float* __restrict__ b,
    const float* __restrict__ gm, const float* __restrict__ be,
    const float* __restrict__ in, float (*out)[PB])
{
  constexpr int J = (OUT_C + 63) / 64;
  float acc[J][PB];
  const float4* w4[J];
#pragma unroll
  for (int j = 0; j < J; ++j) {
    w4[j] = reinterpret_cast<const float4*>(W + (size_t)(lane + 64 * j) * IN_C);
    const float bj = b[lane + 64 * j];
#pragma unroll
    for (int pb = 0; pb < PB; ++pb) acc[j][pb] = bj;
  }
#pragma unroll 2
  for (int k = 0; k < IN_C / 4; ++k) {
    float4 w[J];
#pragma unroll
    for (int j = 0; j < J; ++j) w[j] = w4[j][k];
#pragma unroll
    for (int pb = 0; pb < PB; ++pb) {
      float4 v = reinterpret_cast<const float4*>(in + pb * IN_C)[k];
#pragma unroll
      for (int j = 0; j < J; ++j)
        acc[j][pb] += w[j].x * v.x + w[j].y * v.y + w[j].z * v.z + w[j].w * v.w;
    }
  }
#pragma unroll
  for (int j = 0; j < J; ++j) {
    const int c = lane + 64 * j;
    const float gmc = gm[c], bec = be[c];
#pragma unroll
    for (int pb = 0; pb < PB; ++pb) {
      float a = acc[j][pb];
      a = a >= 0.f ? a : 0.2f * a;            // LeakyReLU(0.2)
      float s1 = rsum32(a);                    // group = 32 consecutive ch
      float s2 = rsum32(a * a);
      float mu = s1 * (1.f / 32.f);
      float var = s2 * (1.f / 32.f) - mu * mu;
      float r = rsqrtf(var + 1e-5f);
      out[j][pb] = (a - mu) * r * gmc + bec;
    }
  }
}

// -------------------------------- init -------------------------------------
__global__ void k_init(unsigned* __restrict__ gv, unsigned* __restrict__ gp,
                       unsigned long long* __restrict__ best,
                       unsigned* __restrict__ rmax, int n)
{
  int i = blockIdx.x * blockDim.x + threadIdx.x;
  if (i < 128) { gv[i] = 0u; gp[i] = 0u; }     // fenc floor (= -inf)
  for (int k = i; k < n; k += gridDim.x * blockDim.x) {
    best[k] = 0ull;
    rmax[k] = 0u;
  }
}

// ------------------------- layers 1-4 + col-max ----------------------------
__global__ __launch_bounds__(256) void k_mlp14(
    const float* __restrict__ x, int n,
    const float* __restrict__ W1, const float* __restrict__ b1, const float* __restrict__ g1, const float* __restrict__ be1,
    const float* __restrict__ W2, const float* __restrict__ b2, const float* __restrict__ g2, const float* __restrict__ be2,
    const float* __restrict__ W3, const float* __restrict__ b3, const float* __restrict__ g3, const float* __restrict__ be3,
    const float* __restrict__ W4, const float* __restrict__ b4, const float* __restrict__ g4, const float* __restrict__ be4,
    float* __restrict__ fOut, unsigned* __restrict__ gMax)
{
  __shared__ float xs[WPB][3 * PB];
  __shared__ float s32[WPB][PB][32];
  __shared__ float s64[WPB][PB][64];
  __shared__ float s128[WPB][PB][128];
  __shared__ float cms[WPB][128];
  const int wave = threadIdx.x >> 6, lane = threadIdx.x & 63;
  const int l31 = lane & 31, grp = lane >> 5;
  float cm0 = -3.4e38f, cm1 = -3.4e38f;
  const int gw = blockIdx.x * WPB + wave;
  const int nw = gridDim.x * WPB;
  const int nb = n / PB;                      // nb % nw == 0 -> uniform trips
  for (int bt = gw; bt < nb; bt += nw) {
    const int p0 = bt * PB;
    if (lane < 3 * PB) xs[wave][lane] = x[(size_t)p0 * 3 + lane];
    __syncthreads();
    // layer1: 3->32, one 32-ch group; two points per pass via half-waves
#pragma unroll
    for (int pb2 = 0; pb2 < PB; pb2 += 2) {
      const int pb = pb2 + grp;
      float a = b1[l31] + W1[l31 * 3] * xs[wave][3 * pb]
              + W1[l31 * 3 + 1] * xs[wave][3 * pb + 1]
              + W1[l31 * 3 + 2] * xs[wave][3 * pb + 2];
      a = a >= 0.f ? a : 0.2f * a;
      float s1 = rsum32(a), s2 = rsum32(a * a);   // half-wave-local groups
      float mu = s1 * (1.f / 32.f);
      float var = s2 * (1.f / 32.f) - mu * mu;
      float r = rsqrtf(var + 1e-5f);
      s32[wave][pb][l31] = (a - mu) * r * g1[l31] + be1[l31];
    }
    __syncthreads();
    float o1[1][PB];
    lin_gn_b<64, 32>(lane, W2, b2, g2, be2, &s32[wave][0][0], o1);
#pragma unroll
    for (int pb = 0; pb < PB; ++pb) s64[wave][pb][lane] = o1[0][pb];
    __syncthreads();
    float o2[2][PB];
    lin_gn_b<128, 64>(lane, W3, b3, g3, be3, &s64[wave][0][0], o2);
#pragma unroll
    for (int pb = 0; pb < PB; ++pb) {
      s128[wave][pb][lane] = o2[0][pb];
      s128[wave][pb][64 + lane] = o2[1][pb];
      fOut[(size_t)(p0 + pb) * 128 + lane] = o2[0][pb];
      fOut[(size_t)(p0 + pb) * 128 + 64 + lane] = o2[1][pb];
    }
    __syncthreads();
    float o3[2][PB];
    lin_gn_b<128, 128>(lane, W4, b4, g4, be4, &s128[wave][0][0], o3);
#pragma unroll
    for (int pb = 0; pb < PB; ++pb) {
      cm0 = fmaxf(cm0, o3[0][pb]);
      cm1 = fmaxf(cm1, o3[1][pb]);
    }
    __syncthreads();
  }
  cms[wave][lane] = cm0; cms[wave][64 + lane] = cm1;
  __syncthreads();
  if (threadIdx.x < 128) {
    float m0 = fmaxf(fmaxf(cms[0][threadIdx.x], cms[1][threadIdx.x]),
                     fmaxf(cms[2][threadIdx.x], cms[3][threadIdx.x]));
    atomicMax(&gMax[threadIdx.x], fenc(m0));
  }
}

// --------------------- layers 5-7 + row normalize + bf16 split -------------
__global__ __launch_bounds__(256) void k_mlp57(
    const float* __restrict__ f, const unsigned* __restrict__ gMax, int n,
    const float* __restrict__ W5, const float* __restrict__ b5, const float* __restrict__ g5, const float* __restrict__ be5,
    const float* __restrict__ W6, const float* __restrict__ b6, const float* __restrict__ g6, const float* __restrict__ be6,
    const float* __restrict__ W7, const float* __restrict__ b7,
    float* __restrict__ ovOut,
    ushort_t* __restrict__ ovH, ushort_t* __restrict__ ovL)
{
  __shared__ float Bin[WPB][PB][256];   // fg = [f | g]     (32 KB)
  __shared__ float C5[WPB][PB][128];    // h5               (16 KB)
  __shared__ float C6[WPB][PB][64];     // h6               (8 KB)
  const int wave = threadIdx.x >> 6, lane = threadIdx.x & 63;
  const float gv0 = fdec(gMax[lane]), gv1 = fdec(gMax[64 + lane]);
#pragma unroll
  for (int pb = 0; pb < PB; ++pb) {     // g half of fg: constant per launch
    Bin[wave][pb][128 + lane] = gv0;
    Bin[wave][pb][192 + lane] = gv1;
  }
  __syncthreads();
  const int gw = blockIdx.x * WPB + wave;
  const int nw = gridDim.x * WPB;
  const int nb = n / PB;
  for (int bt = gw; bt < nb; bt += nw) {
    const int p0 = bt * PB;
#pragma unroll
    for (int pb = 0; pb < PB; ++pb) {
      Bin[wave][pb][lane] = f[(size_t)(p0 + pb) * 128 + lane];
      Bin[wave][pb][64 + lane] = f[(size_t)(p0 + pb) * 128 + 64 + lane];
    }
    __syncthreads();
    float o5[2][PB];
    lin_gn_b<128, 256>(lane, W5, b5, g5, be5, &Bin[wave][0][0], o5);
#pragma unroll
    for (int pb = 0; pb < PB; ++pb) {
      C5[wave][pb][lane] = o5[0][pb];
      C5[wave][pb][64 + lane] = o5[1][pb];
    }
    __syncthreads();
    float o6[1][PB];
    lin_gn_b<64, 128>(lane, W6, b6, g6, be6, &C5[wave][0][0], o6);
#pragma unroll
    for (int pb = 0; pb < PB; ++pb) C6[wave][pb][lane] = o6[0][pb];
    __syncthreads();
    // layer7: plain linear 64->128, batched
    float acc0[PB], acc1[PB];
    {
      const float b70 = b7[lane], b71 = b7[64 + lane];
#pragma unroll
      for (int pb = 0; pb < PB; ++pb) { acc0[pb] = b70; acc1[pb] = b71; }
      const float4* w40 = reinterpret_cast<const float4*>(W7 + (size_t)lane * 64);
      const float4* w41 = reinterpret_cast<const float4*>(W7 + (size_t)(64 + lane) * 64);
#pragma unroll 2
      for (int k = 0; k < 16; ++k) {
        float4 wa = w40[k], wb = w41[k];
#pragma unroll
        for (int pb = 0; pb < PB; ++pb) {
          float4 v = reinterpret_cast<const float4*>(&C6[wave][pb][0])[k];
          acc0[pb] += wa.x * v.x + wa.y * v.y + wa.z * v.z + wa.w * v.w;
          acc1[pb] += wb.x * v.x + wb.y * v.y + wb.z * v.z + wb.w * v.w;
        }
      }
    }
#pragma unroll
    for (int pb = 0; pb < PB; ++pb) {
      float ss = rsum64(acc0[pb] * acc0[pb] + acc1[pb] * acc1[pb]);
      float inv = 1.0f / sqrtf(ss);
      float v0 = acc0[pb] * inv, v1 = acc1[pb] * inv;
      const size_t o = (size_t)(p0 + pb) * 128;
      ovOut[o + lane] = v0;
      ovOut[o + 64 + lane] = v1;
      ushort_t h0 = f2bf(v0), h1 = f2bf(v1);
      ovH[o + lane] = h0;
      ovH[o + 64 + lane] = h1;
      ovL[o + lane] = f2bf(v0 - bf2f(h0));
      ovL[o + 64 + lane] = f2bf(v1 - bf2f(h1));
    }
    __syncthreads();
  }
}

// ---------------- two-phase fused ov@op.T + row argmax (MFMA) --------------
// Block: 128 ov-rows (4 waves x 32) x 64 op-cols per iteration.
// 3-pass bf16 split: s = ahi.bhi + ahi.blo + alo.bhi  (error <~ 4e-6).
// PASS 1: per-row approx max value -> rowmax (fenc atomicMax).
// PASS 2: entries with c >= rowmax - AM_DELTA get exact fp32 re-eval +
//         packed (fenc(exact)<<32 | ~idx) atomicMax -> fp32-argmax semantics.
// C layout (verified): col = lane&31, row = (reg&3)+8*(reg>>2)+4*(lane>>5).
template<int PASS>
__global__ __launch_bounds__(256) void k_amax(
    const ushort_t* __restrict__ avh, const ushort_t* __restrict__ avl,
    const ushort_t* __restrict__ bvh, const ushort_t* __restrict__ bvl,
    const float* __restrict__ ovf, const float* __restrict__ opf,
    int m, unsigned* __restrict__ rowmax, unsigned long long* __restrict__ best)
{
  // [hi/lo][k-chunk 16][col pad 65][8 bf16] = 32.5 KB; 16B-aligned for b128
  __shared__ __align__(16) short lbuf[2][16][65][8];
  const int tid = threadIdx.x;
  const int wave = tid >> 6, lane = tid & 63;
  const int l31 = lane & 31, grp = lane >> 5;
  const int rowBlock = blockIdx.x / AM_CHUNKS;
  const int chunk = blockIdx.x % AM_CHUNKS;
  const int row0 = rowBlock * 128;
  const int jspan = m / AM_CHUNKS;
  const int j0beg = chunk * jspan;
  const int iters = jspan / 64;

  // ---- A fragments, once per block: row = row0 + wave*32 + (lane&31) ----
  const int myrow = row0 + wave * 32 + l31;
  short8v ah[8], al[8];
  {
    const short8v* rh = (const short8v*)(avh + (size_t)myrow * 128);
    const short8v* rl = (const short8v*)(avl + (size_t)myrow * 128);
#pragma unroll
    for (int ks = 0; ks < 8; ++ks) {
      ah[ks] = rh[ks * 2 + grp];        // k = ks*16 + grp*8 + [0..7]
      al[ks] = rl[ks * 2 + grp];
    }
  }

  // staging mapping: thread t loads row j0+(t>>4)+16i, bytes (t&15)*16 (coalesced)
  const int sks = tid & 15;
  const int scol0 = tid >> 4;
  // per-lane LDS fragment base, in 16B units: [grp][l31]
  const short8v* fragH = (const short8v*)&lbuf[0][grp][l31][0];
  const short8v* fragL = (const short8v*)&lbuf[1][grp][l31][0];

  // pass-1 state: running per-row approx max.  pass-2 state: thresholds.
  float rmx[16];
  float thr[16];
#pragma unroll
  for (int r = 0; r < 16; ++r) {
    if constexpr (PASS == 1) {
      rmx[r] = -3.4e38f;
    } else {
      const int row = row0 + wave * 32 + (r & 3) + 8 * (r >> 2) + 4 * grp;
      thr[r] = fdec(rowmax[row]) - AM_DELTA;   // wave-uniform load, broadcast
    }
  }

  // prologue loads (tile 0)
  short8v ph[4], pl[4];
#pragma unroll
  for (int i = 0; i < 4; ++i) {
    int col = scol0 + 16 * i;
    ph[i] = ((const short8v*)bvh)[(size_t)(j0beg + col) * 16 + sks];
    pl[i] = ((const short8v*)bvl)[(size_t)(j0beg + col) * 16 + sks];
  }

  for (int it = 0; it < iters; ++it) {
    __syncthreads();                               // LDS free (prev tile consumed)
#pragma unroll
    for (int i = 0; i < 4; ++i) {
      int col = scol0 + 16 * i;
      *(short8v*)&lbuf[0][sks][col][0] = ph[i];
      *(short8v*)&lbuf[1][sks][col][0] = pl[i];
    }
    __syncthreads();
    if (it + 1 < iters) {                          // prefetch next tile -> regs,
      int j0n = j0beg + (it + 1) * 64;             // overlaps with MFMA below
#pragma unroll
      for (int i = 0; i < 4; ++i) {
        int col = scol0 + 16 * i;
        ph[i] = ((const short8v*)bvh)[(size_t)(j0n + col) * 16 + sks];
        pl[i] = ((const short8v*)bvl)[(size_t)(j0n + col) * 16 + sks];
      }
    }
    const int j0 = j0beg + it * 64;
#pragma unroll
    for (int ct = 0; ct < 2; ++ct) {
      f32x16 c = {};
#pragma unroll
      for (int ks = 0; ks < 8; ++ks) {
        short8v bh = fragH[ks * 130 + ct * 32];    // (ks*2+grp)*65 + l31 + 32ct
        short8v bl = fragL[ks * 130 + ct * 32];
        c = __builtin_amdgcn_mfma_f32_32x32x16_bf16(ah[ks], bh, c, 0, 0, 0);
        c = __builtin_amdgcn_mfma_f32_32x32x16_bf16(ah[ks], bl, c, 0, 0, 0);
        c = __builtin_amdgcn_mfma_f32_32x32x16_bf16(al[ks], bh, c, 0, 0, 0);
      }
      if constexpr (PASS == 1) {
#pragma unroll
        for (int r = 0; r < 16; ++r) rmx[r] = fmaxf(rmx[r], c[r]);
      } else {
        const int j = j0 + ct * 32 + l31;          // this lane's column
        bool any = false;
#pragma unroll
        for (int r = 0; r < 16; ++r) any = any || (c[r] >= thr[r]);
        if (__any((int)any)) {                     // rare: exact re-eval path
#pragma unroll
          for (int r = 0; r < 16; ++r) {
            if (c[r] >= thr[r]) {
              const int row = row0 + wave * 32 + (r & 3) + 8 * (r >> 2) + 4 * grp;
              exact_commit(ovf + (size_t)row * 128, opf + (size_t)j * 128,
                           j, &best[row]);
            }
          }
        }
      }
    }
  }

  if constexpr (PASS == 1) {
    // butterfly fmax across the 32 column-lanes, then one atomic per row
#pragma unroll
    for (int mm = 1; mm <= 16; mm <<= 1) {
#pragma unroll
      for (int r = 0; r < 16; ++r) rmx[r] = fmaxf(rmx[r], __shfl_xor(rmx[r], mm));
    }
    if (l31 == 0) {
#pragma unroll
      for (int r = 0; r < 16; ++r) {
        const int row = row0 + wave * 32 + (r & 3) + 8 * (r >> 2) + 4 * grp;
        atomicMax(&rowmax[row], fenc(rmx[r]));
      }
    }
  }
}

// ----------------------- gather + layer8 + W9 (batched) --------------------
__global__ __launch_bounds__(256) void k_oc(
    const float* __restrict__ ovn, const float* __restrict__ opn,
    const unsigned long long* __restrict__ best, int n,
    const float* __restrict__ W8, const float* __restrict__ b8,
    const float* __restrict__ g8, const float* __restrict__ be8,
    const float* __restrict__ W9, const float* __restrict__ b9,
    float* __restrict__ oc)
{
  __shared__ float Y[WPB][PB][260];     // YXS rows (33.3 KB)
  const int wave = threadIdx.x >> 6, lane = threadIdx.x & 63;
  const int gw = blockIdx.x * WPB + wave;
  const int nw = gridDim.x * WPB;
  const int nb = n / PB;
  const float w9l = W9[lane], b90 = b9[0];
  const float b8l = b8[lane], g8l = g8[lane], be8l = be8[lane];
  const float* w = W8 + (size_t)lane * 257;
  for (int bt = gw; bt < nb; bt += nw) {
    const int p0 = bt * PB;
#pragma unroll
    for (int pb = 0; pb < PB; ++pb) {
      const int p = p0 + pb;
      unsigned long long v = best[p];
      int j = (int)(0xFFFFFFFFu - (unsigned)(v & 0xFFFFFFFFu));
      float Sv = fdec((unsigned)(v >> 32));
      Y[wave][pb][lane]       = ovn[(size_t)p * 128 + lane];
      Y[wave][pb][64 + lane]  = ovn[(size_t)p * 128 + 64 + lane];
      Y[wave][pb][128 + lane] = opn[(size_t)j * 128 + lane];
      Y[wave][pb][192 + lane] = opn[(size_t)j * 128 + 64 + lane];
      if (lane == 0) Y[wave][pb][256] = Sv;
    }
    __syncthreads();
    // layer8: 257 -> 64, batched over PB points; W8 rows are 257-strided
    // (1028 B, not 16B-aligned) -> scalar weight loads, float4 LDS reads.
    float acc[PB];
#pragma unroll
    for (int pb = 0; pb < PB; ++pb) acc[pb] = b8l;
#pragma unroll 2
    for (int k4 = 0; k4 < 64; ++k4) {
      const float w0 = w[k4 * 4], w1 = w[k4 * 4 + 1];
      const float w2 = w[k4 * 4 + 2], w3 = w[k4 * 4 + 3];
#pragma unroll
      for (int pb = 0; pb < PB; ++pb) {
        float4 v = reinterpret_cast<const float4*>(&Y[wave][pb][0])[k4];
        acc[pb] += w0 * v.x + w1 * v.y + w2 * v.z + w3 * v.w;
      }
    }
    {
      const float w256 = w[256];
#pragma unroll
      for (int pb = 0; pb < PB; ++pb) acc[pb] += w256 * Y[wave][pb][256];
    }
#pragma unroll
    for (int pb = 0; pb < PB; ++pb) {
      float a = acc[pb];
      a = a >= 0.f ? a : 0.2f * a;
      float s1 = rsum32(a), s2 = rsum32(a * a);
      float mu = s1 * (1.f / 32.f);
      float var = s2 * (1.f / 32.f) - mu * mu;
      float r = rsqrtf(var + 1e-5f);
      float y = (a - mu) * r * g8l + be8l;
      float tot = rsum64(y * w9l);
      if (lane == 0) oc[p0 + pb] = tot + b90;
    }
    __syncthreads();
  }
}

// ---------------------------------------------------------------------------
extern "C" void kernel_launch(void* const* d_in, const int* in_sizes, int n_in,
                              void* d_out, int out_size, void* d_ws, size_t ws_size,
                              hipStream_t stream)
{
  (void)n_in; (void)out_size; (void)ws_size;
  const float* vtx = (const float*)d_in[0];
  const float* pts = (const float*)d_in[1];
  const float* W1 = (const float*)d_in[2];  const float* b1 = (const float*)d_in[3];
  const float* g1 = (const float*)d_in[4];  const float* be1 = (const float*)d_in[5];
  const float* W2 = (const float*)d_in[6];  const float* b2 = (const float*)d_in[7];
  const float* g2 = (const float*)d_in[8];  const float* be2 = (const float*)d_in[9];
  const float* W3 = (const float*)d_in[10]; const float* b3 = (const float*)d_in[11];
  const float* g3 = (const float*)d_in[12]; const float* be3 = (const float*)d_in[13];
  const float* W4 = (const float*)d_in[14]; const float* b4 = (const float*)d_in[15];
  const float* g4 = (const float*)d_in[16]; const float* be4 = (const float*)d_in[17];
  const float* W5 = (const float*)d_in[18]; const float* b5 = (const float*)d_in[19];
  const float* g5 = (const float*)d_in[20]; const float* be5 = (const float*)d_in[21];
  const float* W6 = (const float*)d_in[22]; const float* b6 = (const float*)d_in[23];
  const float* g6 = (const float*)d_in[24]; const float* be6 = (const float*)d_in[25];
  const float* W7 = (const float*)d_in[26]; const float* b7 = (const float*)d_in[27];
  const float* W8 = (const float*)d_in[28]; const float* b8 = (const float*)d_in[29];
  const float* g8 = (const float*)d_in[30]; const float* be8 = (const float*)d_in[31];
  const float* W9 = (const float*)d_in[32]; const float* b9 = (const float*)d_in[33];

  const int n = in_sizes[0] / 3;   // 16384
  const int m = in_sizes[1] / 3;   // 16384

  // ---- workspace layout (bytes) ----
  char* wsb = (char*)d_ws;
  float* f_v = (float*)wsb;
  size_t f_v_bytes = (size_t)n * 128 * 4;
  float* f_p = (float*)(wsb + f_v_bytes);
  size_t f_p_bytes = (size_t)m * 128 * 4;
  ushort_t* ovh = (ushort_t*)(wsb + f_v_bytes);                       // alias f_p
  ushort_t* ovl = (ushort_t*)(wsb + f_v_bytes + (size_t)n * 128 * 2); // alias f_p
  ushort_t* oph = (ushort_t*)(wsb + f_v_bytes + f_p_bytes);
  ushort_t* opl = (ushort_t*)(wsb + f_v_bytes + f_p_bytes + (size_t)m * 128 * 2);
  char* tail = wsb + f_v_bytes + f_p_bytes + (size_t)m * 128 * 4;
  unsigned* g_v = (unsigned*)tail;
  unsigned* g_p = g_v + 128;
  unsigned long long* best = (unsigned long long*)(g_p + 128);  // 8B aligned
  unsigned* rmaxv = (unsigned*)(best + n);

  float* out_ov = (float*)d_out;                 // n*128
  float* out_op = out_ov + (size_t)n * 128;      // m*128
  float* out_oc = out_op + (size_t)m * 128;      // n

  k_init<<<64, 256, 0, stream>>>(g_v, g_p, best, rmaxv, n);

  k_mlp14<<<MLP_GRID, 256, 0, stream>>>(vtx, n, W1, b1, g1, be1, W2, b2, g2, be2,
                                        W3, b3, g3, be3, W4, b4, g4, be4, f_v, g_v);
  k_mlp14<<<MLP_GRID, 256, 0, stream>>>(pts, m, W1, b1, g1, be1, W2, b2, g2, be2,
                                        W3, b3, g3, be3, W4, b4, g4, be4, f_p, g_p);

  // pts pass FIRST (f_p consumed), then vtx pass may overwrite f_p with ovh/ovl
  k_mlp57<<<MLP_GRID, 256, 0, stream>>>(f_p, g_p, m, W5, b5, g5, be5,
                                        W6, b6, g6, be6, W7, b7, out_op, oph, opl);
  k_mlp57<<<MLP_GRID, 256, 0, stream>>>(f_v, g_v, n, W5, b5, g5, be5,
                                        W6, b6, g6, be6, W7, b7, out_ov, ovh, ovl);

  const int am_grid = (n / 128) * AM_CHUNKS;
  k_amax<1><<<am_grid, 256, 0, stream>>>(ovh, ovl, oph, opl, out_ov, out_op,
                                         m, rmaxv, best);
  k_amax<2><<<am_grid, 256, 0, stream>>>(ovh, ovl, oph, opl, out_ov, out_op,
                                         m, rmaxv, best);

  k_oc<<<MLP_GRID, 256, 0, stream>>>(out_ov, out_op, best, n,
                                     W8, b8, g8, be8, W9, b9, out_oc);
}